// Round 9
// baseline (327.123 us; speedup 1.0000x reference)
//
#include <hip/hip_runtime.h>
#include <hip/hip_bf16.h>
#include <cstddef>

// Problem constants
#define NROWS 4096        // B*N
#define HIDD  128
#define NH    8
#define VD    16

typedef __attribute__((ext_vector_type(8))) short bf16x8;
typedef __attribute__((ext_vector_type(4))) float f32x4;
typedef __attribute__((ext_vector_type(4))) unsigned int u32x4;

__device__ __forceinline__ float gelu_f(float x) {
    // exact (erf) gelu, matching jax.nn.gelu(approximate=False) in fp32
    return 0.5f * x * (1.0f + erff(x * 0.70710678118654752440f));
}

__device__ __forceinline__ unsigned short bf16_rne(float f) {
    union { float f; unsigned u; } x; x.f = f;
    unsigned r = x.u + 0x7FFFu + ((x.u >> 16) & 1u);   // finite inputs only
    return (unsigned short)(r >> 16);
}
__device__ __forceinline__ float bf16_to_f(unsigned short h) {
    union { unsigned u; float f; } x; x.u = ((unsigned)h) << 16;
    return x.f;
}
// packed RNE f32x2 -> bf16x2 (v_cvt_pk path; bit-identical to bf16_rne)
__device__ __forceinline__ unsigned pk_bf16(float a, float b) {
    __hip_bfloat162 t = __float22bfloat162_rn(make_float2(a, b));
    unsigned u; __builtin_memcpy(&u, &t, 4); return u;
}

__device__ __forceinline__ void split8(const float* av, bf16x8& hi, bf16x8& lo) {
    #pragma unroll
    for (int j = 0; j < 8; ++j) {
        unsigned short h = bf16_rne(av[j]);
        unsigned short l = bf16_rne(av[j] - bf16_to_f(h));
        hi[j] = (short)h; lo[j] = (short)l;
    }
}

// A-fragment loaders (verified layout A[m=lane&15][k=quad*8+jj], kt-tiled)
__device__ __forceinline__ void load_a_global(const float* __restrict__ X,
                                              int row0, int lane,
                                              bf16x8* ahi, bf16x8* alo) {
    const int q = lane >> 4, mr = lane & 15;
    const float* xr = X + (size_t)(row0 + mr) * 128 + q * 8;
    #pragma unroll
    for (int kt = 0; kt < 4; ++kt) {
        float av[8];
        *(float4*)(av)     = *(const float4*)(xr + kt * 32);
        *(float4*)(av + 4) = *(const float4*)(xr + kt * 32 + 4);
        split8(av, ahi[kt], alo[kt]);
    }
}
__device__ __forceinline__ void load_a_lds(const float (*xT)[132], int lane,
                                           bf16x8* ahi, bf16x8* alo) {
    const int q = lane >> 4, mr = lane & 15;
    #pragma unroll
    for (int kt = 0; kt < 4; ++kt) {
        float av[8];
        *(float4*)(av)     = *(const float4*)&xT[mr][kt * 32 + q * 8];
        *(float4*)(av + 4) = *(const float4*)&xT[mr][kt * 32 + q * 8 + 4];
        split8(av, ahi[kt], alo[kt]);
    }
}

// split-bf16 triple-MFMA K-step: acc += Ahi@Bhi + Ahi@Blo + Alo@Bhi
__device__ __forceinline__ f32x4 mm3(f32x4 acc, bf16x8 ahi, bf16x8 alo,
                                     const unsigned short* __restrict__ bp, int kt) {
    bf16x8 bhi = *(const bf16x8*)(bp + kt * 512);
    bf16x8 blo = *(const bf16x8*)(bp + 16384 + kt * 512);
    acc = __builtin_amdgcn_mfma_f32_16x16x32_bf16(ahi, bhi, acc, 0, 0, 0);
    acc = __builtin_amdgcn_mfma_f32_16x16x32_bf16(ahi, blo, acc, 0, 0, 0);
    acc = __builtin_amdgcn_mfma_f32_16x16x32_bf16(alo, bhi, acc, 0, 0, 0);
    return acc;
}

// store one fp32 value as bf16 into the blocked V layout read by the attn B-frag
__device__ __forceinline__ void vstore(unsigned short* __restrict__ vt,
                                       int r, int c, float v) {
    int bb = r >> 11, n = r & 2047;
    int jt = n >> 5, q2 = (n >> 3) & 3, jj = n & 7;
    int h = c >> 4, dd = c & 15;
    size_t off = (((size_t)(bb * 8 + h) * 64 + jt) * 4 + q2) * 128 + (dd << 3) + jj;
    vt[off] = bf16_rne(v);
}

// V-projection of a 16-row LDS tile into vblk (4 waves x 2 col-tiles)
__device__ __forceinline__ void vproj_lds(const float (*xT)[132], int row0,
                                          const unsigned short* __restrict__ Vw,
                                          unsigned short* __restrict__ vblk) {
    const int tid = threadIdx.x, wave = tid >> 6, lane = tid & 63;
    const int q = lane >> 4, mr = lane & 15;
    bf16x8 ahi[4], alo[4];
    load_a_lds(xT, lane, ahi, alo);
    #pragma unroll
    for (int ct = 0; ct < 2; ++ct) {
        int nt = wave * 2 + ct;
        const unsigned short* bp = Vw + (size_t)nt * 2048 + lane * 8;
        f32x4 acc = (f32x4){0.f, 0.f, 0.f, 0.f};
        #pragma unroll
        for (int kt = 0; kt < 4; ++kt) acc = mm3(acc, ahi[kt], alo[kt], bp, kt);
        int c = nt * 16 + mr;
        #pragma unroll
        for (int reg = 0; reg < 4; ++reg)
            vstore(vblk, row0 + q * 4 + reg, c, acc[reg]);
    }
}

// ---------------------------------------------------------------------------
// Weight prep + per-row 5th-percentile ranks, fused into one launch.
// ---------------------------------------------------------------------------
struct PrepArgs { const float* src[25]; unsigned vwmask; };

__global__ __launch_bounds__(256) void prep_percentile_kernel(
    PrepArgs a, unsigned short* __restrict__ dst,
    const float* __restrict__ m, float* __restrict__ m102, float* __restrict__ m103)
{
    if (blockIdx.x < 100) {
        const int mat = blockIdx.x >> 2, chunk = blockIdx.x & 3;
        const float* __restrict__ W = a.src[mat];
        const int vw = (a.vwmask >> mat) & 1;
        unsigned short* __restrict__ base = dst + (size_t)mat * 32768;
        for (int o = chunk * 4096 + threadIdx.x; o < chunk * 4096 + 4096; o += 256) {
            int nt = o >> 11, kt = (o >> 9) & 3, q = (o >> 7) & 3;
            int n16 = (o >> 3) & 15, jj = o & 7;
            int k = kt * 32 + q * 8 + jj;
            float w = vw ? W[nt * 2048 + k * 16 + n16]
                         : W[k * 128 + nt * 16 + n16];
            unsigned short h = bf16_rne(w);
            unsigned short l = bf16_rne(w - bf16_to_f(h));
            base[o] = h;
            base[16384 + o] = l;
        }
        return;
    }

    __shared__ int   cnt[256];
    __shared__ int   cum[256];
    __shared__ float buf[192];
    __shared__ int   nc;
    __shared__ int   sb0, sb1, sbase;

    const int row = blockIdx.x - 100;         // 0..4095
    const int t   = threadIdx.x;
    const float* mr = m + (size_t)row * 2048;

    float4 aa = *(const float4*)(mr + t * 8);
    float4 cc = *(const float4*)(mr + t * 8 + 4);
    float v[8] = {aa.x, aa.y, aa.z, aa.w, cc.x, cc.y, cc.z, cc.w};

    cnt[t] = 0;
    if (t == 0) nc = 0;
    __syncthreads();

    int bidx[8];
    #pragma unroll
    for (int i = 0; i < 8; ++i) {
        int bi = (int)(v[i] * 256.0f);
        bi = bi < 0 ? 0 : (bi > 255 ? 255 : bi);
        bidx[i] = bi;
        atomicAdd(&cnt[bi], 1);
    }
    __syncthreads();

    if (t < 64) {
        int c0 = cnt[t * 4], c1 = cnt[t * 4 + 1], c2 = cnt[t * 4 + 2], c3 = cnt[t * 4 + 3];
        int s1 = c0 + c1, s2 = s1 + c2, s3 = s2 + c3;
        int sc = s3;
        #pragma unroll
        for (int off = 1; off < 64; off <<= 1) {
            int o = __shfl_up(sc, off);
            if (t >= off) sc += o;
        }
        int base = sc - s3;
        cum[t * 4]     = base + c0;
        cum[t * 4 + 1] = base + s1;
        cum[t * 4 + 2] = base + s2;
        cum[t * 4 + 3] = base + s3;
    }
    __syncthreads();

    {
        int cprev = (t == 0) ? 0 : cum[t - 1];
        int cthis = cum[t];
        if (cprev < 103 && 103 <= cthis) { sb0 = t; sbase = cprev; }
        if (cprev < 104 && 104 <= cthis) { sb1 = t; }
    }
    __syncthreads();

    const int b0 = sb0, b1 = sb1, base = sbase;
    #pragma unroll
    for (int i = 0; i < 8; ++i) {
        if (bidx[i] >= b0 && bidx[i] <= b1) {
            int p = atomicAdd(&nc, 1);
            if (p < 192) buf[p] = v[i];
        }
    }
    __syncthreads();

    int n = nc; if (n > 192) n = 192;
    if (t < n) {
        float x = buf[t];
        int rk = base;
        for (int j = 0; j < n; ++j) {
            float y = buf[j];
            rk += (y < x || (y == x && j < t)) ? 1 : 0;
        }
        if (rk == 102) m102[row] = x;
        if (rk == 103) m103[row] = x;
    }
}

// ---------------------------------------------------------------------------
// Encoder fused with the first V-projection.
// ---------------------------------------------------------------------------
__global__ __launch_bounds__(256) void encoder_vproj_kernel(
    const float* __restrict__ inp, const float* __restrict__ W,
    const float* __restrict__ b, float* __restrict__ ben,
    const unsigned short* __restrict__ Vw, unsigned short* __restrict__ vblk)
{
    __shared__ float xT[16][132];
    const int tid = threadIdx.x;
    const int row0 = blockIdx.x * 16;
    const int ri = tid >> 4, c0 = (tid & 15) * 8;
    const int row = row0 + ri;
    float x0 = inp[row * 3], x1 = inp[row * 3 + 1], x2 = inp[row * 3 + 2];
    float o[8];
    #pragma unroll
    for (int j = 0; j < 8; ++j) {
        int c = c0 + j;
        o[j] = gelu_f(x0 * W[c] + x1 * W[128 + c] + x2 * W[256 + c] + b[c]);
        xT[ri][c0 + j] = o[j];
    }
    *(float4*)(ben + (size_t)row * 128 + c0)     = *(float4*)(o);
    *(float4*)(ben + (size_t)row * 128 + c0 + 4) = *(float4*)(o + 4);
    __syncthreads();
    vproj_lds(xT, row0, Vw, vblk);
}

// ---------------------------------------------------------------------------
// K1: fused MFMA flash mhpa + first MLP matmul — R9: 1024 threads = 16 waves
// = 4 waves/SIMD (was 8 waves / 2 per SIMD; grid=256=1 block/CU so TLP was
// the latency-hiding bottleneck). j split 8 ways (8 jt of 32 j per wave).
// Per jt: prefetch jt+1's m-float4s + 4 V-frags, masked exp (v_exp_f32),
// packed bf16 A-frag, MFMA vs V + vs all-ones B (row-sums in MFMA).
// LDS: 8 j-partials (64 KB) + sums + bh tile = 76.7 KB, 1 block/CU.
// ---------------------------------------------------------------------------
__global__ __launch_bounds__(1024) void attn_mlp_kernel(
    const float* __restrict__ m_dist,
    const unsigned short* __restrict__ vblk,
    const float* __restrict__ rvec,
    const float* __restrict__ m102, const float* __restrict__ m103,
    const unsigned short* __restrict__ W1b, const float* __restrict__ b1,
    float* __restrict__ bt, int masked)
{
    __shared__ float partLDS[8][16][128];    // 64 KB
    __shared__ float sumLDS[8][8][16];       // 4 KB
    __shared__ float bhT[16][132];           // 8.25 KB

    const int tid  = threadIdx.x;
    const int wave = tid >> 6, lane = tid & 63;
    const int hg = wave & 1, jq = wave >> 1;       // head-group(2), j-eighth(8)
    const int q = lane >> 4, rn = lane & 15;       // quad, A-row-in-tile
    const int row0 = blockIdx.x * 16;
    const int row  = row0 + rn;
    const int b    = row0 >> 11;                   // 16 | 2048 -> same batch
    const int n    = row & 2047;

    float r2[4], c2[4], thr[4];
    {
        const double pos = 5.0 / 100.0 * 2047.0;   // tfp percentile position
        const float FRAC = (float)(pos - 102.0);
        const float OM   = 1.0f - FRAC;
        float t102 = m102[row], t103 = m103[row];
        #pragma unroll
        for (int hh = 0; hh < 4; ++hh) {
            float r = rvec[hg * 4 + hh];
            r2[hh] = r * r;
            c2[hh] = -r2[hh] * 1.44269504088896340736f;  // -r^2*log2(e)
            thr[hh] = masked ? ((t102 * r2[hh]) * OM + (t103 * r2[hh]) * FRAC)
                             : 3.4028235e38f;
        }
    }

    const float* mrow = m_dist + ((size_t)b << 22) + ((size_t)n << 11);
    const unsigned short* vbase = vblk + (((size_t)(b * 8 + hg * 4)) << 15);

    f32x4 acc[4], accs[4];
    #pragma unroll
    for (int hh = 0; hh < 4; ++hh) {
        acc[hh]  = (f32x4){0.f, 0.f, 0.f, 0.f};
        accs[hh] = (f32x4){0.f, 0.f, 0.f, 0.f};
    }
    bf16x8 vones;
    #pragma unroll
    for (int j = 0; j < 8; ++j) vones[j] = (short)0x3F80;   // bf16 1.0

    const int jbeg = jq * 8, jend = jbeg + 8;      // 8 jt x 32 j = 256 j/wave
    float mv[8]; bf16x8 bfr[4];
    {
        const int jb = (jbeg << 5) + (q << 3);
        *(float4*)(mv)     = *(const float4*)(mrow + jb);
        *(float4*)(mv + 4) = *(const float4*)(mrow + jb + 4);
        #pragma unroll
        for (int hh = 0; hh < 4; ++hh)
            bfr[hh] = *(const bf16x8*)(vbase + ((size_t)hh << 15)
                                        + ((size_t)jbeg << 9) + (lane << 3));
    }

    if (masked) {
        for (int jt = jbeg; jt < jend; ++jt) {
            const int jn = (jt + 1 < jend) ? jt + 1 : jt;   // clamped prefetch
            float mvn[8]; bf16x8 bfn[4];
            const int jbn = (jn << 5) + (q << 3);
            *(float4*)(mvn)     = *(const float4*)(mrow + jbn);
            *(float4*)(mvn + 4) = *(const float4*)(mrow + jbn + 4);
            #pragma unroll
            for (int hh = 0; hh < 4; ++hh)
                bfn[hh] = *(const bf16x8*)(vbase + ((size_t)hh << 15)
                                            + ((size_t)jn << 9) + (lane << 3));

            #pragma unroll
            for (int hh = 0; hh < 4; ++hh) {
                float p[8];
                #pragma unroll
                for (int jj = 0; jj < 8; ++jj) {
                    float sd = mv[jj] * r2[hh];
                    float e  = __builtin_amdgcn_exp2f(mv[jj] * c2[hh]);
                    p[jj] = (sd <= thr[hh]) ? e : 0.f;
                }
                u32x4 af;
                af[0] = pk_bf16(p[0], p[1]); af[1] = pk_bf16(p[2], p[3]);
                af[2] = pk_bf16(p[4], p[5]); af[3] = pk_bf16(p[6], p[7]);
                bf16x8 afrag = __builtin_bit_cast(bf16x8, af);
                acc[hh]  = __builtin_amdgcn_mfma_f32_16x16x32_bf16(afrag, bfr[hh], acc[hh], 0, 0, 0);
                accs[hh] = __builtin_amdgcn_mfma_f32_16x16x32_bf16(afrag, vones,   accs[hh], 0, 0, 0);
            }
            #pragma unroll
            for (int jj = 0; jj < 8; ++jj) mv[jj] = mvn[jj];
            #pragma unroll
            for (int hh = 0; hh < 4; ++hh) bfr[hh] = bfn[hh];
        }
    } else {
        for (int jt = jbeg; jt < jend; ++jt) {
            const int jn = (jt + 1 < jend) ? jt + 1 : jt;
            float mvn[8]; bf16x8 bfn[4];
            const int jbn = (jn << 5) + (q << 3);
            *(float4*)(mvn)     = *(const float4*)(mrow + jbn);
            *(float4*)(mvn + 4) = *(const float4*)(mrow + jbn + 4);
            #pragma unroll
            for (int hh = 0; hh < 4; ++hh)
                bfn[hh] = *(const bf16x8*)(vbase + ((size_t)hh << 15)
                                            + ((size_t)jn << 9) + (lane << 3));

            #pragma unroll
            for (int hh = 0; hh < 4; ++hh) {
                float p[8];
                #pragma unroll
                for (int jj = 0; jj < 8; ++jj)
                    p[jj] = __builtin_amdgcn_exp2f(mv[jj] * c2[hh]);
                u32x4 af;
                af[0] = pk_bf16(p[0], p[1]); af[1] = pk_bf16(p[2], p[3]);
                af[2] = pk_bf16(p[4], p[5]); af[3] = pk_bf16(p[6], p[7]);
                bf16x8 afrag = __builtin_bit_cast(bf16x8, af);
                acc[hh]  = __builtin_amdgcn_mfma_f32_16x16x32_bf16(afrag, bfr[hh], acc[hh], 0, 0, 0);
                accs[hh] = __builtin_amdgcn_mfma_f32_16x16x32_bf16(afrag, vones,   accs[hh], 0, 0, 0);
            }
            #pragma unroll
            for (int jj = 0; jj < 8; ++jj) mv[jj] = mvn[jj];
            #pragma unroll
            for (int hh = 0; hh < 4; ++hh) bfr[hh] = bfn[hh];
        }
    }

    // row-sums: accs D-layout row = q*4+reg (value replicated across cols);
    // col-0 lanes (rn==0, q=0..3) cover all 16 tile rows.
    if (rn == 0) {
        #pragma unroll
        for (int hh = 0; hh < 4; ++hh)
            #pragma unroll
            for (int reg = 0; reg < 4; ++reg)
                sumLDS[jq][hg * 4 + hh][q * 4 + reg] = accs[hh][reg];
    }
    #pragma unroll
    for (int hh = 0; hh < 4; ++hh) {
        #pragma unroll
        for (int reg = 0; reg < 4; ++reg)
            partLDS[jq][q * 4 + reg][(hg * 4 + hh) * 16 + rn] = acc[hh][reg];
    }
    __syncthreads();

    // epilogue -> bh tile in LDS (2 elements per thread)
    {
        int e0 = tid << 1;
        int ri = e0 >> 7, c0e = e0 & 127, h = c0e >> 4;
        float sx = 0.f, sy = 0.f, l = 0.f;
        #pragma unroll
        for (int k = 0; k < 8; ++k) {
            sx += partLDS[k][ri][c0e];
            sy += partLDS[k][ri][c0e + 1];
            l  += sumLDS[k][h][ri];
        }
        float inv = 1.0f / l;
        bhT[ri][c0e]     = gelu_f(sx * inv);
        bhT[ri][c0e + 1] = gelu_f(sy * inv);
    }
    __syncthreads();

    // stage 2: bt = gelu(bh @ W1 + b1); waves 0-7 = 8 col-tiles
    if (wave < 8) {
        bf16x8 ahi[4], alo[4];
        load_a_lds(bhT, lane, ahi, alo);
        const unsigned short* bp = W1b + (size_t)wave * 2048 + lane * 8;
        f32x4 a2 = (f32x4){0.f, 0.f, 0.f, 0.f};
        #pragma unroll
        for (int kt = 0; kt < 4; ++kt) a2 = mm3(a2, ahi[kt], alo[kt], bp, kt);
        const int c = wave * 16 + rn;
        const float bv = b1[c];
        #pragma unroll
        for (int reg = 0; reg < 4; ++reg)
            bt[(size_t)(row0 + q * 4 + reg) * 128 + c] = gelu_f(a2[reg] + bv);
    }
}

// ---------------------------------------------------------------------------
// K2: xout = gelu(A1@B1 + bias1 + A2@B2 + bias2), then project the same 16
// rows through Vw into vblk for the next mhpa. 256 thr = 4 waves x 2 ct.
// ---------------------------------------------------------------------------
__global__ __launch_bounds__(256) void mm2_vproj_kernel(
    const float* __restrict__ A1, const unsigned short* __restrict__ B1,
    const float* __restrict__ bias1,
    const float* __restrict__ A2, const unsigned short* __restrict__ B2,
    const float* __restrict__ bias2,
    float* __restrict__ xout,
    const unsigned short* __restrict__ Vw, unsigned short* __restrict__ vblk)
{
    __shared__ float xT[16][132];
    const int tid = threadIdx.x, wave = tid >> 6, lane = tid & 63;
    const int q = lane >> 4, mr = lane & 15;
    const int row0 = blockIdx.x * 16;

    bf16x8 a1h[4], a1l[4], a2h[4], a2l[4];
    load_a_global(A1, row0, lane, a1h, a1l);
    load_a_global(A2, row0, lane, a2h, a2l);

    #pragma unroll
    for (int ct = 0; ct < 2; ++ct) {
        int nt = wave * 2 + ct;
        const unsigned short* bp1 = B1 + (size_t)nt * 2048 + lane * 8;
        const unsigned short* bp2 = B2 + (size_t)nt * 2048 + lane * 8;
        f32x4 acc = (f32x4){0.f, 0.f, 0.f, 0.f};
        #pragma unroll
        for (int kt = 0; kt < 4; ++kt) acc = mm3(acc, a1h[kt], a1l[kt], bp1, kt);
        #pragma unroll
        for (int kt = 0; kt < 4; ++kt) acc = mm3(acc, a2h[kt], a2l[kt], bp2, kt);
        int c = nt * 16 + mr;
        float bv = bias1[c] + bias2[c];
        #pragma unroll
        for (int reg = 0; reg < 4; ++reg) {
            float v = gelu_f(acc[reg] + bv);
            xout[(size_t)(row0 + q * 4 + reg) * 128 + c] = v;
            xT[q * 4 + reg][c] = v;
        }
    }
    __syncthreads();
    vproj_lds(xT, row0, Vw, vblk);
}

// ---------------------------------------------------------------------------
// Terminal K2: de = gelu(A1@B1 + A2@B2 + biases); t = gelu(de@DW1 + db1);
// out = t @ de_W2 + de_b2. de/t never leave the block.
// ---------------------------------------------------------------------------
__global__ __launch_bounds__(256) void mm2_decoder_kernel(
    const float* __restrict__ A1, const unsigned short* __restrict__ B1,
    const float* __restrict__ bias1,
    const float* __restrict__ A2, const unsigned short* __restrict__ B2,
    const float* __restrict__ bias2,
    const unsigned short* __restrict__ DW1, const float* __restrict__ db1,
    const float* __restrict__ de_W2, const float* __restrict__ de_b2,
    float* __restrict__ out)
{
    __shared__ float xT[16][132];
    __shared__ float tT[16][132];
    const int tid = threadIdx.x, wave = tid >> 6, lane = tid & 63;
    const int q = lane >> 4, mr = lane & 15;
    const int row0 = blockIdx.x * 16;

    bf16x8 a1h[4], a1l[4], a2h[4], a2l[4];
    load_a_global(A1, row0, lane, a1h, a1l);
    load_a_global(A2, row0, lane, a2h, a2l);

    #pragma unroll
    for (int ct = 0; ct < 2; ++ct) {
        int nt = wave * 2 + ct;
        const unsigned short* bp1 = B1 + (size_t)nt * 2048 + lane * 8;
        const unsigned short* bp2 = B2 + (size_t)nt * 2048 + lane * 8;
        f32x4 acc = (f32x4){0.f, 0.f, 0.f, 0.f};
        #pragma unroll
        for (int kt = 0; kt < 4; ++kt) acc = mm3(acc, a1h[kt], a1l[kt], bp1, kt);
        #pragma unroll
        for (int kt = 0; kt < 4; ++kt) acc = mm3(acc, a2h[kt], a2l[kt], bp2, kt);
        int c = nt * 16 + mr;
        float bv = bias1[c] + bias2[c];
        #pragma unroll
        for (int reg = 0; reg < 4; ++reg)
            xT[q * 4 + reg][c] = gelu_f(acc[reg] + bv);
    }
    __syncthreads();

    // t = gelu(de @ DW1 + db1)
    {
        bf16x8 ahi[4], alo[4];
        load_a_lds(xT, lane, ahi, alo);
        #pragma unroll
        for (int ct = 0; ct < 2; ++ct) {
            int nt = wave * 2 + ct;
            const unsigned short* bp = DW1 + (size_t)nt * 2048 + lane * 8;
            f32x4 acc = (f32x4){0.f, 0.f, 0.f, 0.f};
            #pragma unroll
            for (int kt = 0; kt < 4; ++kt) acc = mm3(acc, ahi[kt], alo[kt], bp, kt);
            int c = nt * 16 + mr;
            #pragma unroll
            for (int reg = 0; reg < 4; ++reg)
                tT[q * 4 + reg][c] = gelu_f(acc[reg] + db1[c]);
        }
    }
    __syncthreads();

    // out = t @ de_W2 + de_b2  (16-lane groups reduce one row each)
    {
        int r = tid >> 4, ch = tid & 15;
        const float* tp = &tT[r][ch * 8];
        const float* wp = de_W2 + ch * 8;
        float p = 0.f;
        #pragma unroll
        for (int j = 0; j < 8; ++j) p += tp[j] * wp[j];
        p += __shfl_xor(p, 1); p += __shfl_xor(p, 2);
        p += __shfl_xor(p, 4); p += __shfl_xor(p, 8);
        if (ch == 0) out[row0 + r] = p + de_b2[0];
    }
}

// ---------------------------------------------------------------------------
extern "C" void kernel_launch(void* const* d_in, const int* in_sizes, int n_in,
                              void* d_out, int out_size, void* d_ws, size_t ws_size,
                              hipStream_t stream)
{
    (void)in_sizes; (void)n_in; (void)out_size; (void)ws_size;
    const float* m_dist  = (const float*)d_in[0];
    const float* inputs  = (const float*)d_in[1];
    const float* en_W    = (const float*)d_in[2];
    const float* en_b    = (const float*)d_in[3];
    const float* down_r  = (const float*)d_in[4];
    const float* down_w  = (const float*)d_in[5];
    const float* mlp1_W1 = (const float*)d_in[6];
    const float* mlp1_b1 = (const float*)d_in[7];
    const float* mlp1_W2 = (const float*)d_in[8];
    const float* mlp1_b2 = (const float*)d_in[9];
    const float* w1_W    = (const float*)d_in[10];
    const float* w1_b    = (const float*)d_in[11];
    const float* pa_r    = (const float*)d_in[12];
    const float* pa_w    = (const float*)d_in[13];
    const float* blk_W1  = (const float*)d_in[14];
    const float* blk_b1  = (const float*)d_in[15];
    const float* blk_W2  = (const float*)d_in[16];
    const float* blk_b2  = (const float*)d_in[17];
    const float* wi_W    = (const float*)d_in[18];
    const float* wi_b    = (const float*)d_in[19];
    const float* up_r    = (const float*)d_in[20];
    const float* up_w    = (const float*)d_in[21];
    const float* mlp2_W1 = (const float*)d_in[22];
    const float* mlp2_b1 = (const float*)d_in[23];
    const float* mlp2_W2 = (const float*)d_in[24];
    const float* mlp2_b2 = (const float*)d_in[25];
    const float* w2_W    = (const float*)d_in[26];
    const float* w2_b    = (const float*)d_in[27];
    const float* de_W1   = (const float*)d_in[28];
    const float* de_b1   = (const float*)d_in[29];
    const float* de_W2   = (const float*)d_in[30];
    const float* de_b2   = (const float*)d_in[31];
    float* out = (float*)d_out;

    // workspace layout (floats)
    const size_t BUF = (size_t)NROWS * HIDD;   // 524288
    float* w     = (float*)d_ws;
    float* ben   = w;
    float* bx0   = w + 1 * BUF;
    float* bx1   = w + 2 * BUF;
    float* bt    = w + 3 * BUF;
    unsigned short* vblk = (unsigned short*)(w + 4 * BUF);  // 1 MB bf16 blocked V
    float* m102  = w + 5 * BUF;
    float* m103  = m102 + NROWS;
    unsigned short* wcvt = (unsigned short*)(m103 + NROWS); // 25 x 64 KB

    enum { CW_DOWN = 0, CW_MLP1W1 = 1, CW_MLP1W2 = 2, CW_W1 = 3,
           CW_PA = 4 /*4..7*/, CW_BLKW1 = 8, CW_BLKW2 = 12, CW_WI = 16,
           CW_UP = 20, CW_MLP2W1 = 21, CW_MLP2W2 = 22, CW_W2 = 23, CW_DE1 = 24 };
    PrepArgs pa;
    pa.src[CW_DOWN]   = down_w;
    pa.src[CW_MLP1W1] = mlp1_W1;
    pa.src[CW_MLP1W2] = mlp1_W2;
    pa.src[CW_W1]     = w1_W;
    for (int i = 0; i < 4; ++i) {
        pa.src[CW_PA + i]    = pa_w   + (size_t)i * NH * HIDD * VD;
        pa.src[CW_BLKW1 + i] = blk_W1 + (size_t)i * HIDD * HIDD;
        pa.src[CW_BLKW2 + i] = blk_W2 + (size_t)i * HIDD * HIDD;
        pa.src[CW_WI + i]    = wi_W   + (size_t)i * HIDD * HIDD;
    }
    pa.src[CW_UP]     = up_w;
    pa.src[CW_MLP2W1] = mlp2_W1;
    pa.src[CW_MLP2W2] = mlp2_W2;
    pa.src[CW_W2]     = w2_W;
    pa.src[CW_DE1]    = de_W1;
    pa.vwmask = (1u << CW_DOWN) | (0xFu << CW_PA) | (1u << CW_UP);

    auto CW = [&](int slot) { return wcvt + (size_t)slot * 32768; };

    dim3 b256(256), b1024(1024);
    dim3 gT(NROWS / 16);                // 256 tile-blocks

    auto K1 = [&](const float* rv, int masked, int w1slot, const float* b1v) {
        attn_mlp_kernel<<<gT, b1024, 0, stream>>>(m_dist, vblk, rv, m102, m103,
                                                  CW(w1slot), b1v, bt, masked);
    };
    auto K2 = [&](int s1, const float* bias1, const float* A2, int s2,
                  const float* bias2, float* xo, int vslot) {
        mm2_vproj_kernel<<<gT, b256, 0, stream>>>(bt, CW(s1), bias1,
                                                  A2, CW(s2), bias2,
                                                  xo, CW(vslot), vblk);
    };

    // weight prep + percentile thresholds (one launch)
    prep_percentile_kernel<<<dim3(100 + NROWS), b256, 0, stream>>>(
        pa, wcvt, m_dist, m102, m103);

    // encoder + V-projection for the down mhpa
    encoder_vproj_kernel<<<gT, b256, 0, stream>>>(inputs, en_W, en_b, ben,
                                                  CW(CW_DOWN), vblk);

    // down block
    K1(down_r, 1, CW_MLP1W1, mlp1_b1);
    K2(CW_MLP1W2, mlp1_b2, ben, CW_W1, w1_b, bx0, CW_PA + 0);

    // 4 processor blocks (ping-pong bx0/bx1)
    float* xin = bx0;
    float* xout = bx1;
    for (int i = 0; i < 4; ++i) {
        K1(pa_r + (size_t)i * NH, 0, CW_BLKW1 + i, blk_b1 + (size_t)i * HIDD);
        K2(CW_BLKW2 + i, blk_b2 + (size_t)i * HIDD,
           xin, CW_WI + i, wi_b + (size_t)i * HIDD,
           xout, (i < 3) ? (CW_PA + i + 1) : CW_UP);
        float* tmp = xin; xin = xout; xout = tmp;
    }
    // xin now holds x

    // up block + decoder + final (terminal fused kernel)
    K1(up_r, 1, CW_MLP2W1, mlp2_b1);
    mm2_decoder_kernel<<<gT, b256, 0, stream>>>(
        bt, CW(CW_MLP2W2), mlp2_b2,
        xin, CW(CW_W2), w2_b,
        CW(CW_DE1), de_b1, de_W2, de_b2, out);
}

// Round 10
// 316.171 us; speedup vs baseline: 1.0346x; 1.0346x over previous
//
#include <hip/hip_runtime.h>
#include <hip/hip_bf16.h>
#include <cstddef>

// Problem constants
#define NROWS 4096        // B*N
#define HIDD  128
#define NH    8
#define VD    16

typedef __attribute__((ext_vector_type(8))) short bf16x8;
typedef __attribute__((ext_vector_type(4))) float f32x4;
typedef __attribute__((ext_vector_type(4))) unsigned int u32x4;

__device__ __forceinline__ float gelu_f(float x) {
    // exact (erf) gelu, matching jax.nn.gelu(approximate=False) in fp32
    return 0.5f * x * (1.0f + erff(x * 0.70710678118654752440f));
}

__device__ __forceinline__ unsigned short bf16_rne(float f) {
    union { float f; unsigned u; } x; x.f = f;
    unsigned r = x.u + 0x7FFFu + ((x.u >> 16) & 1u);   // finite inputs only
    return (unsigned short)(r >> 16);
}
__device__ __forceinline__ float bf16_to_f(unsigned short h) {
    union { unsigned u; float f; } x; x.u = ((unsigned)h) << 16;
    return x.f;
}
// packed RNE f32x2 -> bf16x2 (v_cvt_pk path; bit-identical to bf16_rne)
__device__ __forceinline__ unsigned pk_bf16(float a, float b) {
    __hip_bfloat162 t = __float22bfloat162_rn(make_float2(a, b));
    unsigned u; __builtin_memcpy(&u, &t, 4); return u;
}

__device__ __forceinline__ void split8(const float* av, bf16x8& hi, bf16x8& lo) {
    #pragma unroll
    for (int j = 0; j < 8; ++j) {
        unsigned short h = bf16_rne(av[j]);
        unsigned short l = bf16_rne(av[j] - bf16_to_f(h));
        hi[j] = (short)h; lo[j] = (short)l;
    }
}

// A-fragment loaders (verified layout A[m=lane&15][k=quad*8+jj], kt-tiled)
__device__ __forceinline__ void load_a_global(const float* __restrict__ X,
                                              int row0, int lane,
                                              bf16x8* ahi, bf16x8* alo) {
    const int q = lane >> 4, mr = lane & 15;
    const float* xr = X + (size_t)(row0 + mr) * 128 + q * 8;
    #pragma unroll
    for (int kt = 0; kt < 4; ++kt) {
        float av[8];
        *(float4*)(av)     = *(const float4*)(xr + kt * 32);
        *(float4*)(av + 4) = *(const float4*)(xr + kt * 32 + 4);
        split8(av, ahi[kt], alo[kt]);
    }
}
__device__ __forceinline__ void load_a_lds(const float (*xT)[132], int lane,
                                           bf16x8* ahi, bf16x8* alo) {
    const int q = lane >> 4, mr = lane & 15;
    #pragma unroll
    for (int kt = 0; kt < 4; ++kt) {
        float av[8];
        *(float4*)(av)     = *(const float4*)&xT[mr][kt * 32 + q * 8];
        *(float4*)(av + 4) = *(const float4*)&xT[mr][kt * 32 + q * 8 + 4];
        split8(av, ahi[kt], alo[kt]);
    }
}

// split-bf16 triple-MFMA K-step: acc += Ahi@Bhi + Ahi@Blo + Alo@Bhi
__device__ __forceinline__ f32x4 mm3(f32x4 acc, bf16x8 ahi, bf16x8 alo,
                                     const unsigned short* __restrict__ bp, int kt) {
    bf16x8 bhi = *(const bf16x8*)(bp + kt * 512);
    bf16x8 blo = *(const bf16x8*)(bp + 16384 + kt * 512);
    acc = __builtin_amdgcn_mfma_f32_16x16x32_bf16(ahi, bhi, acc, 0, 0, 0);
    acc = __builtin_amdgcn_mfma_f32_16x16x32_bf16(ahi, blo, acc, 0, 0, 0);
    acc = __builtin_amdgcn_mfma_f32_16x16x32_bf16(alo, bhi, acc, 0, 0, 0);
    return acc;
}

// V-projection of a 16-row LDS tile into vblk (4 waves x 2 col-tiles).
// R10: the 4 regs of a col-tile map to contiguous jj in the blocked layout,
// so pack them into one 8-byte uint2 store (was 8 scattered 2-byte stores).
__device__ __forceinline__ void vproj_lds(const float (*xT)[132], int row0,
                                          const unsigned short* __restrict__ Vw,
                                          unsigned short* __restrict__ vblk) {
    const int tid = threadIdx.x, wave = tid >> 6, lane = tid & 63;
    const int q = lane >> 4, mr = lane & 15;
    bf16x8 ahi[4], alo[4];
    load_a_lds(xT, lane, ahi, alo);
    #pragma unroll
    for (int ct = 0; ct < 2; ++ct) {
        int nt = wave * 2 + ct;
        const unsigned short* bp = Vw + (size_t)nt * 2048 + lane * 8;
        f32x4 acc = (f32x4){0.f, 0.f, 0.f, 0.f};
        #pragma unroll
        for (int kt = 0; kt < 4; ++kt) acc = mm3(acc, ahi[kt], alo[kt], bp, kt);
        int c = nt * 16 + mr;
        int r0 = row0 + q * 4;                 // rows r0..r0+3 -> jj..jj+3
        int bb = r0 >> 11, n = r0 & 2047;
        int jt = n >> 5, q2 = (n >> 3) & 3, jj = n & 7;
        int h = c >> 4, dd = c & 15;
        size_t off = (((size_t)(bb * 8 + h) * 64 + jt) * 4 + q2) * 128
                   + (dd << 3) + jj;
        uint2 st = make_uint2(pk_bf16(acc[0], acc[1]), pk_bf16(acc[2], acc[3]));
        *(uint2*)(vblk + off) = st;            // 8B-aligned (jj in {0,4})
    }
}

// ---------------------------------------------------------------------------
// Weight prep + per-row 5th-percentile ranks, fused into one launch.
// ---------------------------------------------------------------------------
struct PrepArgs { const float* src[25]; unsigned vwmask; };

__global__ __launch_bounds__(256) void prep_percentile_kernel(
    PrepArgs a, unsigned short* __restrict__ dst,
    const float* __restrict__ m, float* __restrict__ m102, float* __restrict__ m103)
{
    if (blockIdx.x < 100) {
        const int mat = blockIdx.x >> 2, chunk = blockIdx.x & 3;
        const float* __restrict__ W = a.src[mat];
        const int vw = (a.vwmask >> mat) & 1;
        unsigned short* __restrict__ base = dst + (size_t)mat * 32768;
        for (int o = chunk * 4096 + threadIdx.x; o < chunk * 4096 + 4096; o += 256) {
            int nt = o >> 11, kt = (o >> 9) & 3, q = (o >> 7) & 3;
            int n16 = (o >> 3) & 15, jj = o & 7;
            int k = kt * 32 + q * 8 + jj;
            float w = vw ? W[nt * 2048 + k * 16 + n16]
                         : W[k * 128 + nt * 16 + n16];
            unsigned short h = bf16_rne(w);
            unsigned short l = bf16_rne(w - bf16_to_f(h));
            base[o] = h;
            base[16384 + o] = l;
        }
        return;
    }

    __shared__ int   cnt[256];
    __shared__ int   cum[256];
    __shared__ float buf[192];
    __shared__ int   nc;
    __shared__ int   sb0, sb1, sbase;

    const int row = blockIdx.x - 100;         // 0..4095
    const int t   = threadIdx.x;
    const float* mr = m + (size_t)row * 2048;

    float4 aa = *(const float4*)(mr + t * 8);
    float4 cc = *(const float4*)(mr + t * 8 + 4);
    float v[8] = {aa.x, aa.y, aa.z, aa.w, cc.x, cc.y, cc.z, cc.w};

    cnt[t] = 0;
    if (t == 0) nc = 0;
    __syncthreads();

    int bidx[8];
    #pragma unroll
    for (int i = 0; i < 8; ++i) {
        int bi = (int)(v[i] * 256.0f);
        bi = bi < 0 ? 0 : (bi > 255 ? 255 : bi);
        bidx[i] = bi;
        atomicAdd(&cnt[bi], 1);
    }
    __syncthreads();

    if (t < 64) {
        int c0 = cnt[t * 4], c1 = cnt[t * 4 + 1], c2 = cnt[t * 4 + 2], c3 = cnt[t * 4 + 3];
        int s1 = c0 + c1, s2 = s1 + c2, s3 = s2 + c3;
        int sc = s3;
        #pragma unroll
        for (int off = 1; off < 64; off <<= 1) {
            int o = __shfl_up(sc, off);
            if (t >= off) sc += o;
        }
        int base = sc - s3;
        cum[t * 4]     = base + c0;
        cum[t * 4 + 1] = base + s1;
        cum[t * 4 + 2] = base + s2;
        cum[t * 4 + 3] = base + s3;
    }
    __syncthreads();

    {
        int cprev = (t == 0) ? 0 : cum[t - 1];
        int cthis = cum[t];
        if (cprev < 103 && 103 <= cthis) { sb0 = t; sbase = cprev; }
        if (cprev < 104 && 104 <= cthis) { sb1 = t; }
    }
    __syncthreads();

    const int b0 = sb0, b1 = sb1, base = sbase;
    #pragma unroll
    for (int i = 0; i < 8; ++i) {
        if (bidx[i] >= b0 && bidx[i] <= b1) {
            int p = atomicAdd(&nc, 1);
            if (p < 192) buf[p] = v[i];
        }
    }
    __syncthreads();

    int n = nc; if (n > 192) n = 192;
    if (t < n) {
        float x = buf[t];
        int rk = base;
        for (int j = 0; j < n; ++j) {
            float y = buf[j];
            rk += (y < x || (y == x && j < t)) ? 1 : 0;
        }
        if (rk == 102) m102[row] = x;
        if (rk == 103) m103[row] = x;
    }
}

// ---------------------------------------------------------------------------
// Encoder fused with the first V-projection.
// ---------------------------------------------------------------------------
__global__ __launch_bounds__(256) void encoder_vproj_kernel(
    const float* __restrict__ inp, const float* __restrict__ W,
    const float* __restrict__ b, float* __restrict__ ben,
    const unsigned short* __restrict__ Vw, unsigned short* __restrict__ vblk)
{
    __shared__ float xT[16][132];
    const int tid = threadIdx.x;
    const int row0 = blockIdx.x * 16;
    const int ri = tid >> 4, c0 = (tid & 15) * 8;
    const int row = row0 + ri;
    float x0 = inp[row * 3], x1 = inp[row * 3 + 1], x2 = inp[row * 3 + 2];
    float o[8];
    #pragma unroll
    for (int j = 0; j < 8; ++j) {
        int c = c0 + j;
        o[j] = gelu_f(x0 * W[c] + x1 * W[128 + c] + x2 * W[256 + c] + b[c]);
        xT[ri][c0 + j] = o[j];
    }
    *(float4*)(ben + (size_t)row * 128 + c0)     = *(float4*)(o);
    *(float4*)(ben + (size_t)row * 128 + c0 + 4) = *(float4*)(o + 4);
    __syncthreads();
    vproj_lds(xT, row0, Vw, vblk);
}

// ---------------------------------------------------------------------------
// K1: fused MFMA flash mhpa + first MLP matmul.
// R10: back to the R8 shape (512 thr = 8 waves; R9's 16-wave variant
// regressed -> the loop is issue-bound, not latency-bound). jt loop unrolled
// x2 with A/B register ping-pong: kills the 24 v_mov pipeline-copy per jt
// (~10% of loop issue slots). Mask path selected by a wave-uniform branch.
// ---------------------------------------------------------------------------
__global__ __launch_bounds__(512) void attn_mlp_kernel(
    const float* __restrict__ m_dist,
    const unsigned short* __restrict__ vblk,
    const float* __restrict__ rvec,
    const float* __restrict__ m102, const float* __restrict__ m103,
    const unsigned short* __restrict__ W1b, const float* __restrict__ b1,
    float* __restrict__ bt, int masked)
{
    __shared__ float partLDS[4][16][128];    // 32 KB
    __shared__ float sumLDS[4][8][16];       // 2 KB
    __shared__ float bhT[16][132];           // 8.25 KB

    const int tid  = threadIdx.x;
    const int wave = tid >> 6, lane = tid & 63;
    const int hg = wave & 1, jq = wave >> 1;       // head-group(2), j-quarter(4)
    const int q = lane >> 4, rn = lane & 15;       // quad, A-row-in-tile
    const int row0 = blockIdx.x * 16;
    const int row  = row0 + rn;
    const int b    = row0 >> 11;                   // 16 | 2048 -> same batch
    const int n    = row & 2047;

    float r2[4], c2[4], thr[4];
    {
        const double pos = 5.0 / 100.0 * 2047.0;   // tfp percentile position
        const float FRAC = (float)(pos - 102.0);
        const float OM   = 1.0f - FRAC;
        float t102 = m102[row], t103 = m103[row];
        #pragma unroll
        for (int hh = 0; hh < 4; ++hh) {
            float r = rvec[hg * 4 + hh];
            r2[hh] = r * r;
            c2[hh] = -r2[hh] * 1.44269504088896340736f;  // -r^2*log2(e)
            thr[hh] = masked ? ((t102 * r2[hh]) * OM + (t103 * r2[hh]) * FRAC)
                             : 3.4028235e38f;
        }
    }

    const float* mrow = m_dist + ((size_t)b << 22) + ((size_t)n << 11);
    const unsigned short* vbase = vblk + (((size_t)(b * 8 + hg * 4)) << 15);

    f32x4 acc[4], accs[4];
    #pragma unroll
    for (int hh = 0; hh < 4; ++hh) {
        acc[hh]  = (f32x4){0.f, 0.f, 0.f, 0.f};
        accs[hh] = (f32x4){0.f, 0.f, 0.f, 0.f};
    }
    bf16x8 vones;
    #pragma unroll
    for (int j = 0; j < 8; ++j) vones[j] = (short)0x3F80;   // bf16 1.0

    const int jbeg = jq * 16, jend = jbeg + 16;    // 16 jt x 32 j per wave

    float mvA[8], mvB[8]; bf16x8 bfA[4], bfB[4];

    auto loadjt = [&](int jt, float* mv, bf16x8* bf) {
        const int jb = (jt << 5) + (q << 3);
        *(float4*)(mv)     = *(const float4*)(mrow + jb);
        *(float4*)(mv + 4) = *(const float4*)(mrow + jb + 4);
        #pragma unroll
        for (int hh = 0; hh < 4; ++hh)
            bf[hh] = *(const bf16x8*)(vbase + ((size_t)hh << 15)
                                       + ((size_t)jt << 9) + (lane << 3));
    };
    auto compute = [&](const float* mv, const bf16x8* bf) {
        #pragma unroll
        for (int hh = 0; hh < 4; ++hh) {
            float p[8];
            if (masked) {
                #pragma unroll
                for (int jj = 0; jj < 8; ++jj) {
                    float sd = mv[jj] * r2[hh];
                    float e  = __builtin_amdgcn_exp2f(mv[jj] * c2[hh]);
                    p[jj] = (sd <= thr[hh]) ? e : 0.f;
                }
            } else {
                #pragma unroll
                for (int jj = 0; jj < 8; ++jj)
                    p[jj] = __builtin_amdgcn_exp2f(mv[jj] * c2[hh]);
            }
            u32x4 af;
            af[0] = pk_bf16(p[0], p[1]); af[1] = pk_bf16(p[2], p[3]);
            af[2] = pk_bf16(p[4], p[5]); af[3] = pk_bf16(p[6], p[7]);
            bf16x8 afrag = __builtin_bit_cast(bf16x8, af);
            acc[hh]  = __builtin_amdgcn_mfma_f32_16x16x32_bf16(afrag, bf[hh], acc[hh], 0, 0, 0);
            accs[hh] = __builtin_amdgcn_mfma_f32_16x16x32_bf16(afrag, vones,  accs[hh], 0, 0, 0);
        }
    };

    loadjt(jbeg, mvA, bfA);
    for (int jt = jbeg; jt < jend; jt += 2) {
        loadjt(jt + 1, mvB, bfB);                  // prefetch odd
        compute(mvA, bfA);
        int j2 = (jt + 2 < jend) ? jt + 2 : jend - 1;  // clamped (uniform)
        loadjt(j2, mvA, bfA);                      // prefetch next even
        compute(mvB, bfB);
    }

    // row-sums: accs D-layout row = q*4+reg (value replicated across cols);
    // col-0 lanes (rn==0, q=0..3) cover all 16 tile rows.
    if (rn == 0) {
        #pragma unroll
        for (int hh = 0; hh < 4; ++hh)
            #pragma unroll
            for (int reg = 0; reg < 4; ++reg)
                sumLDS[jq][hg * 4 + hh][q * 4 + reg] = accs[hh][reg];
    }
    #pragma unroll
    for (int hh = 0; hh < 4; ++hh) {
        #pragma unroll
        for (int reg = 0; reg < 4; ++reg)
            partLDS[jq][q * 4 + reg][(hg * 4 + hh) * 16 + rn] = acc[hh][reg];
    }
    __syncthreads();

    // epilogue -> bh tile in LDS (no global round-trip)
    {
        int e0 = tid << 2;
        int ri = e0 >> 7, c0e = e0 & 127, h = c0e >> 4;
        float4 s = *(const float4*)&partLDS[0][ri][c0e];
        #pragma unroll
        for (int k = 1; k < 4; ++k) {
            float4 pz = *(const float4*)&partLDS[k][ri][c0e];
            s.x += pz.x; s.y += pz.y; s.z += pz.z; s.w += pz.w;
        }
        float l = sumLDS[0][h][ri] + sumLDS[1][h][ri]
                + sumLDS[2][h][ri] + sumLDS[3][h][ri];
        float inv = 1.0f / l;
        float4 o;
        o.x = gelu_f(s.x * inv); o.y = gelu_f(s.y * inv);
        o.z = gelu_f(s.z * inv); o.w = gelu_f(s.w * inv);
        *(float4*)&bhT[ri][c0e] = o;
    }
    __syncthreads();

    // stage 2: bt = gelu(bh @ W1 + b1); 8 waves = 8 col-tiles
    {
        bf16x8 ahi[4], alo[4];
        load_a_lds(bhT, lane, ahi, alo);
        const unsigned short* bp = W1b + (size_t)wave * 2048 + lane * 8;
        f32x4 a2 = (f32x4){0.f, 0.f, 0.f, 0.f};
        #pragma unroll
        for (int kt = 0; kt < 4; ++kt) a2 = mm3(a2, ahi[kt], alo[kt], bp, kt);
        const int c = wave * 16 + rn;
        const float bv = b1[c];
        #pragma unroll
        for (int reg = 0; reg < 4; ++reg)
            bt[(size_t)(row0 + q * 4 + reg) * 128 + c] = gelu_f(a2[reg] + bv);
    }
}

// ---------------------------------------------------------------------------
// K2: xout = gelu(A1@B1 + bias1 + A2@B2 + bias2), then project the same 16
// rows through Vw into vblk for the next mhpa. 256 thr = 4 waves x 2 ct.
// ---------------------------------------------------------------------------
__global__ __launch_bounds__(256) void mm2_vproj_kernel(
    const float* __restrict__ A1, const unsigned short* __restrict__ B1,
    const float* __restrict__ bias1,
    const float* __restrict__ A2, const unsigned short* __restrict__ B2,
    const float* __restrict__ bias2,
    float* __restrict__ xout,
    const unsigned short* __restrict__ Vw, unsigned short* __restrict__ vblk)
{
    __shared__ float xT[16][132];
    const int tid = threadIdx.x, wave = tid >> 6, lane = tid & 63;
    const int q = lane >> 4, mr = lane & 15;
    const int row0 = blockIdx.x * 16;

    bf16x8 a1h[4], a1l[4], a2h[4], a2l[4];
    load_a_global(A1, row0, lane, a1h, a1l);
    load_a_global(A2, row0, lane, a2h, a2l);

    #pragma unroll
    for (int ct = 0; ct < 2; ++ct) {
        int nt = wave * 2 + ct;
        const unsigned short* bp1 = B1 + (size_t)nt * 2048 + lane * 8;
        const unsigned short* bp2 = B2 + (size_t)nt * 2048 + lane * 8;
        f32x4 acc = (f32x4){0.f, 0.f, 0.f, 0.f};
        #pragma unroll
        for (int kt = 0; kt < 4; ++kt) acc = mm3(acc, a1h[kt], a1l[kt], bp1, kt);
        #pragma unroll
        for (int kt = 0; kt < 4; ++kt) acc = mm3(acc, a2h[kt], a2l[kt], bp2, kt);
        int c = nt * 16 + mr;
        float bv = bias1[c] + bias2[c];
        #pragma unroll
        for (int reg = 0; reg < 4; ++reg) {
            float v = gelu_f(acc[reg] + bv);
            xout[(size_t)(row0 + q * 4 + reg) * 128 + c] = v;
            xT[q * 4 + reg][c] = v;
        }
    }
    __syncthreads();
    vproj_lds(xT, row0, Vw, vblk);
}

// ---------------------------------------------------------------------------
// Terminal K2: de = gelu(A1@B1 + A2@B2 + biases); t = gelu(de@DW1 + db1);
// out = t @ de_W2 + de_b2. de/t never leave the block.
// ---------------------------------------------------------------------------
__global__ __launch_bounds__(256) void mm2_decoder_kernel(
    const float* __restrict__ A1, const unsigned short* __restrict__ B1,
    const float* __restrict__ bias1,
    const float* __restrict__ A2, const unsigned short* __restrict__ B2,
    const float* __restrict__ bias2,
    const unsigned short* __restrict__ DW1, const float* __restrict__ db1,
    const float* __restrict__ de_W2, const float* __restrict__ de_b2,
    float* __restrict__ out)
{
    __shared__ float xT[16][132];
    __shared__ float tT[16][132];
    const int tid = threadIdx.x, wave = tid >> 6, lane = tid & 63;
    const int q = lane >> 4, mr = lane & 15;
    const int row0 = blockIdx.x * 16;

    bf16x8 a1h[4], a1l[4], a2h[4], a2l[4];
    load_a_global(A1, row0, lane, a1h, a1l);
    load_a_global(A2, row0, lane, a2h, a2l);

    #pragma unroll
    for (int ct = 0; ct < 2; ++ct) {
        int nt = wave * 2 + ct;
        const unsigned short* bp1 = B1 + (size_t)nt * 2048 + lane * 8;
        const unsigned short* bp2 = B2 + (size_t)nt * 2048 + lane * 8;
        f32x4 acc = (f32x4){0.f, 0.f, 0.f, 0.f};
        #pragma unroll
        for (int kt = 0; kt < 4; ++kt) acc = mm3(acc, a1h[kt], a1l[kt], bp1, kt);
        #pragma unroll
        for (int kt = 0; kt < 4; ++kt) acc = mm3(acc, a2h[kt], a2l[kt], bp2, kt);
        int c = nt * 16 + mr;
        float bv = bias1[c] + bias2[c];
        #pragma unroll
        for (int reg = 0; reg < 4; ++reg)
            xT[q * 4 + reg][c] = gelu_f(acc[reg] + bv);
    }
    __syncthreads();

    // t = gelu(de @ DW1 + db1)
    {
        bf16x8 ahi[4], alo[4];
        load_a_lds(xT, lane, ahi, alo);
        #pragma unroll
        for (int ct = 0; ct < 2; ++ct) {
            int nt = wave * 2 + ct;
            const unsigned short* bp = DW1 + (size_t)nt * 2048 + lane * 8;
            f32x4 acc = (f32x4){0.f, 0.f, 0.f, 0.f};
            #pragma unroll
            for (int kt = 0; kt < 4; ++kt) acc = mm3(acc, ahi[kt], alo[kt], bp, kt);
            int c = nt * 16 + mr;
            #pragma unroll
            for (int reg = 0; reg < 4; ++reg)
                tT[q * 4 + reg][c] = gelu_f(acc[reg] + db1[c]);
        }
    }
    __syncthreads();

    // out = t @ de_W2 + de_b2  (16-lane groups reduce one row each)
    {
        int r = tid >> 4, ch = tid & 15;
        const float* tp = &tT[r][ch * 8];
        const float* wp = de_W2 + ch * 8;
        float p = 0.f;
        #pragma unroll
        for (int j = 0; j < 8; ++j) p += tp[j] * wp[j];
        p += __shfl_xor(p, 1); p += __shfl_xor(p, 2);
        p += __shfl_xor(p, 4); p += __shfl_xor(p, 8);
        if (ch == 0) out[row0 + r] = p + de_b2[0];
    }
}

// ---------------------------------------------------------------------------
extern "C" void kernel_launch(void* const* d_in, const int* in_sizes, int n_in,
                              void* d_out, int out_size, void* d_ws, size_t ws_size,
                              hipStream_t stream)
{
    (void)in_sizes; (void)n_in; (void)out_size; (void)ws_size;
    const float* m_dist  = (const float*)d_in[0];
    const float* inputs  = (const float*)d_in[1];
    const float* en_W    = (const float*)d_in[2];
    const float* en_b    = (const float*)d_in[3];
    const float* down_r  = (const float*)d_in[4];
    const float* down_w  = (const float*)d_in[5];
    const float* mlp1_W1 = (const float*)d_in[6];
    const float* mlp1_b1 = (const float*)d_in[7];
    const float* mlp1_W2 = (const float*)d_in[8];
    const float* mlp1_b2 = (const float*)d_in[9];
    const float* w1_W    = (const float*)d_in[10];
    const float* w1_b    = (const float*)d_in[11];
    const float* pa_r    = (const float*)d_in[12];
    const float* pa_w    = (const float*)d_in[13];
    const float* blk_W1  = (const float*)d_in[14];
    const float* blk_b1  = (const float*)d_in[15];
    const float* blk_W2  = (const float*)d_in[16];
    const float* blk_b2  = (const float*)d_in[17];
    const float* wi_W    = (const float*)d_in[18];
    const float* wi_b    = (const float*)d_in[19];
    const float* up_r    = (const float*)d_in[20];
    const float* up_w    = (const float*)d_in[21];
    const float* mlp2_W1 = (const float*)d_in[22];
    const float* mlp2_b1 = (const float*)d_in[23];
    const float* mlp2_W2 = (const float*)d_in[24];
    const float* mlp2_b2 = (const float*)d_in[25];
    const float* w2_W    = (const float*)d_in[26];
    const float* w2_b    = (const float*)d_in[27];
    const float* de_W1   = (const float*)d_in[28];
    const float* de_b1   = (const float*)d_in[29];
    const float* de_W2   = (const float*)d_in[30];
    const float* de_b2   = (const float*)d_in[31];
    float* out = (float*)d_out;

    // workspace layout (floats)
    const size_t BUF = (size_t)NROWS * HIDD;   // 524288
    float* w     = (float*)d_ws;
    float* ben   = w;
    float* bx0   = w + 1 * BUF;
    float* bx1   = w + 2 * BUF;
    float* bt    = w + 3 * BUF;
    unsigned short* vblk = (unsigned short*)(w + 4 * BUF);  // 1 MB bf16 blocked V
    float* m102  = w + 5 * BUF;
    float* m103  = m102 + NROWS;
    unsigned short* wcvt = (unsigned short*)(m103 + NROWS); // 25 x 64 KB

    enum { CW_DOWN = 0, CW_MLP1W1 = 1, CW_MLP1W2 = 2, CW_W1 = 3,
           CW_PA = 4 /*4..7*/, CW_BLKW1 = 8, CW_BLKW2 = 12, CW_WI = 16,
           CW_UP = 20, CW_MLP2W1 = 21, CW_MLP2W2 = 22, CW_W2 = 23, CW_DE1 = 24 };
    PrepArgs pa;
    pa.src[CW_DOWN]   = down_w;
    pa.src[CW_MLP1W1] = mlp1_W1;
    pa.src[CW_MLP1W2] = mlp1_W2;
    pa.src[CW_W1]     = w1_W;
    for (int i = 0; i < 4; ++i) {
        pa.src[CW_PA + i]    = pa_w   + (size_t)i * NH * HIDD * VD;
        pa.src[CW_BLKW1 + i] = blk_W1 + (size_t)i * HIDD * HIDD;
        pa.src[CW_BLKW2 + i] = blk_W2 + (size_t)i * HIDD * HIDD;
        pa.src[CW_WI + i]    = wi_W   + (size_t)i * HIDD * HIDD;
    }
    pa.src[CW_UP]     = up_w;
    pa.src[CW_MLP2W1] = mlp2_W1;
    pa.src[CW_MLP2W2] = mlp2_W2;
    pa.src[CW_W2]     = w2_W;
    pa.src[CW_DE1]    = de_W1;
    pa.vwmask = (1u << CW_DOWN) | (0xFu << CW_PA) | (1u << CW_UP);

    auto CW = [&](int slot) { return wcvt + (size_t)slot * 32768; };

    dim3 b256(256), b512(512);
    dim3 gT(NROWS / 16);                // 256 tile-blocks

    auto K1 = [&](const float* rv, int masked, int w1slot, const float* b1v) {
        attn_mlp_kernel<<<gT, b512, 0, stream>>>(m_dist, vblk, rv, m102, m103,
                                                 CW(w1slot), b1v, bt, masked);
    };
    auto K2 = [&](int s1, const float* bias1, const float* A2, int s2,
                  const float* bias2, float* xo, int vslot) {
        mm2_vproj_kernel<<<gT, b256, 0, stream>>>(bt, CW(s1), bias1,
                                                  A2, CW(s2), bias2,
                                                  xo, CW(vslot), vblk);
    };

    // weight prep + percentile thresholds (one launch)
    prep_percentile_kernel<<<dim3(100 + NROWS), b256, 0, stream>>>(
        pa, wcvt, m_dist, m102, m103);

    // encoder + V-projection for the down mhpa
    encoder_vproj_kernel<<<gT, b256, 0, stream>>>(inputs, en_W, en_b, ben,
                                                  CW(CW_DOWN), vblk);

    // down block
    K1(down_r, 1, CW_MLP1W1, mlp1_b1);
    K2(CW_MLP1W2, mlp1_b2, ben, CW_W1, w1_b, bx0, CW_PA + 0);

    // 4 processor blocks (ping-pong bx0/bx1)
    float* xin = bx0;
    float* xout = bx1;
    for (int i = 0; i < 4; ++i) {
        K1(pa_r + (size_t)i * NH, 0, CW_BLKW1 + i, blk_b1 + (size_t)i * HIDD);
        K2(CW_BLKW2 + i, blk_b2 + (size_t)i * HIDD,
           xin, CW_WI + i, wi_b + (size_t)i * HIDD,
           xout, (i < 3) ? (CW_PA + i + 1) : CW_UP);
        float* tmp = xin; xin = xout; xout = tmp;
    }
    // xin now holds x

    // up block + decoder + final (terminal fused kernel)
    K1(up_r, 1, CW_MLP2W1, mlp2_b1);
    mm2_decoder_kernel<<<gT, b256, 0, stream>>>(
        bt, CW(CW_MLP2W2), mlp2_b2,
        xin, CW(CW_W2), w2_b,
        CW(CW_DE1), de_b1, de_W2, de_b2, out);
}

// Round 11
// 289.892 us; speedup vs baseline: 1.1284x; 1.0907x over previous
//
#include <hip/hip_runtime.h>
#include <hip/hip_bf16.h>
#include <cstddef>

// Problem constants
#define NROWS 4096        // B*N
#define HIDD  128
#define NH    8
#define VD    16

typedef __attribute__((ext_vector_type(8))) short bf16x8;
typedef __attribute__((ext_vector_type(4))) float f32x4;
typedef __attribute__((ext_vector_type(4))) unsigned int u32x4;

__device__ __forceinline__ float gelu_f(float x) {
    // exact (erf) gelu, matching jax.nn.gelu(approximate=False) in fp32
    return 0.5f * x * (1.0f + erff(x * 0.70710678118654752440f));
}

__device__ __forceinline__ unsigned short bf16_rne(float f) {
    union { float f; unsigned u; } x; x.f = f;
    unsigned r = x.u + 0x7FFFu + ((x.u >> 16) & 1u);   // finite inputs only
    return (unsigned short)(r >> 16);
}
__device__ __forceinline__ float bf16_to_f(unsigned short h) {
    union { unsigned u; float f; } x; x.u = ((unsigned)h) << 16;
    return x.f;
}
// packed RNE f32x2 -> bf16x2 (v_cvt_pk path; bit-identical to bf16_rne)
__device__ __forceinline__ unsigned pk_bf16(float a, float b) {
    __hip_bfloat162 t = __float22bfloat162_rn(make_float2(a, b));
    unsigned u; __builtin_memcpy(&u, &t, 4); return u;
}

__device__ __forceinline__ void split8(const float* av, bf16x8& hi, bf16x8& lo) {
    #pragma unroll
    for (int j = 0; j < 8; ++j) {
        unsigned short h = bf16_rne(av[j]);
        unsigned short l = bf16_rne(av[j] - bf16_to_f(h));
        hi[j] = (short)h; lo[j] = (short)l;
    }
}

// A-fragment loaders (verified layout A[m=lane&15][k=quad*8+jj], kt-tiled)
__device__ __forceinline__ void load_a_global(const float* __restrict__ X,
                                              int row0, int lane,
                                              bf16x8* ahi, bf16x8* alo) {
    const int q = lane >> 4, mr = lane & 15;
    const float* xr = X + (size_t)(row0 + mr) * 128 + q * 8;
    #pragma unroll
    for (int kt = 0; kt < 4; ++kt) {
        float av[8];
        *(float4*)(av)     = *(const float4*)(xr + kt * 32);
        *(float4*)(av + 4) = *(const float4*)(xr + kt * 32 + 4);
        split8(av, ahi[kt], alo[kt]);
    }
}
__device__ __forceinline__ void load_a_lds(const float (*xT)[132], int lane,
                                           bf16x8* ahi, bf16x8* alo) {
    const int q = lane >> 4, mr = lane & 15;
    #pragma unroll
    for (int kt = 0; kt < 4; ++kt) {
        float av[8];
        *(float4*)(av)     = *(const float4*)&xT[mr][kt * 32 + q * 8];
        *(float4*)(av + 4) = *(const float4*)&xT[mr][kt * 32 + q * 8 + 4];
        split8(av, ahi[kt], alo[kt]);
    }
}

// split-bf16 triple-MFMA K-step: acc += Ahi@Bhi + Ahi@Blo + Alo@Bhi
__device__ __forceinline__ f32x4 mm3(f32x4 acc, bf16x8 ahi, bf16x8 alo,
                                     const unsigned short* __restrict__ bp, int kt) {
    bf16x8 bhi = *(const bf16x8*)(bp + kt * 512);
    bf16x8 blo = *(const bf16x8*)(bp + 16384 + kt * 512);
    acc = __builtin_amdgcn_mfma_f32_16x16x32_bf16(ahi, bhi, acc, 0, 0, 0);
    acc = __builtin_amdgcn_mfma_f32_16x16x32_bf16(ahi, blo, acc, 0, 0, 0);
    acc = __builtin_amdgcn_mfma_f32_16x16x32_bf16(alo, bhi, acc, 0, 0, 0);
    return acc;
}

// V-projection of a 16-row LDS tile into vblk — 4-wave (2 ct) variant used by
// the encoder kernel. Packed uint2 store (contiguous jj).
__device__ __forceinline__ void vproj_lds(const float (*xT)[132], int row0,
                                          const unsigned short* __restrict__ Vw,
                                          unsigned short* __restrict__ vblk) {
    const int tid = threadIdx.x, wave = tid >> 6, lane = tid & 63;
    const int q = lane >> 4, mr = lane & 15;
    bf16x8 ahi[4], alo[4];
    load_a_lds(xT, lane, ahi, alo);
    #pragma unroll
    for (int ct = 0; ct < 2; ++ct) {
        int nt = wave * 2 + ct;
        const unsigned short* bp = Vw + (size_t)nt * 2048 + lane * 8;
        f32x4 acc = (f32x4){0.f, 0.f, 0.f, 0.f};
        #pragma unroll
        for (int kt = 0; kt < 4; ++kt) acc = mm3(acc, ahi[kt], alo[kt], bp, kt);
        int c = nt * 16 + mr;
        int r0 = row0 + q * 4;
        int bb = r0 >> 11, n = r0 & 2047;
        int jt = n >> 5, q2 = (n >> 3) & 3, jj = n & 7;
        int h = c >> 4, dd = c & 15;
        size_t off = (((size_t)(bb * 8 + h) * 64 + jt) * 4 + q2) * 128
                   + (dd << 3) + jj;
        uint2 st = make_uint2(pk_bf16(acc[0], acc[1]), pk_bf16(acc[2], acc[3]));
        *(uint2*)(vblk + off) = st;
    }
}

// 8-wave (1 ct per wave) helpers for the fused stage kernel -----------------

// dst = gelu(src @ Wb + bias), 16x128 tile, LDS->LDS
__device__ __forceinline__ void mm_lds_tile(const float (*src)[132], float (*dst)[132],
                                            const unsigned short* __restrict__ Wb,
                                            const float* __restrict__ bias,
                                            int wave, int lane) {
    bf16x8 ahi[4], alo[4];
    load_a_lds(src, lane, ahi, alo);
    const unsigned short* bp = Wb + (size_t)wave * 2048 + lane * 8;
    f32x4 acc = (f32x4){0.f, 0.f, 0.f, 0.f};
    #pragma unroll
    for (int kt = 0; kt < 4; ++kt) acc = mm3(acc, ahi[kt], alo[kt], bp, kt);
    const int q = lane >> 4, rn = lane & 15, c = wave * 16 + rn;
    const float bv = bias[c];
    #pragma unroll
    for (int reg = 0; reg < 4; ++reg)
        dst[q * 4 + reg][c] = gelu_f(acc[reg] + bv);
}

// xT = gelu(A1(LDS)@B1 + A2(global rows row0..)@B2 + bias1 + bias2);
// optional mirror to global xout.
__device__ __forceinline__ void mm2_tile(const float (*A1)[132],
                                         const float* __restrict__ A2, int row0,
                                         const unsigned short* __restrict__ B1,
                                         const float* __restrict__ bias1,
                                         const unsigned short* __restrict__ B2,
                                         const float* __restrict__ bias2,
                                         float* __restrict__ xout, float (*xT)[132],
                                         int wave, int lane) {
    bf16x8 a1h[4], a1l[4], a2h[4], a2l[4];
    load_a_lds(A1, lane, a1h, a1l);
    load_a_global(A2, row0, lane, a2h, a2l);
    const unsigned short* bp1 = B1 + (size_t)wave * 2048 + lane * 8;
    const unsigned short* bp2 = B2 + (size_t)wave * 2048 + lane * 8;
    f32x4 acc = (f32x4){0.f, 0.f, 0.f, 0.f};
    #pragma unroll
    for (int kt = 0; kt < 4; ++kt) acc = mm3(acc, a1h[kt], a1l[kt], bp1, kt);
    #pragma unroll
    for (int kt = 0; kt < 4; ++kt) acc = mm3(acc, a2h[kt], a2l[kt], bp2, kt);
    const int q = lane >> 4, rn = lane & 15, c = wave * 16 + rn;
    const float bv = bias1[c] + bias2[c];
    #pragma unroll
    for (int reg = 0; reg < 4; ++reg) {
        float v = gelu_f(acc[reg] + bv);
        if (xout) xout[(size_t)(row0 + q * 4 + reg) * 128 + c] = v;
        xT[q * 4 + reg][c] = v;
    }
}

// vproj, 8 waves x 1 ct
__device__ __forceinline__ void vproj8(const float (*xT)[132], int row0,
                                       const unsigned short* __restrict__ Vw,
                                       unsigned short* __restrict__ vout,
                                       int wave, int lane) {
    bf16x8 ahi[4], alo[4];
    load_a_lds(xT, lane, ahi, alo);
    const unsigned short* bp = Vw + (size_t)wave * 2048 + lane * 8;
    f32x4 acc = (f32x4){0.f, 0.f, 0.f, 0.f};
    #pragma unroll
    for (int kt = 0; kt < 4; ++kt) acc = mm3(acc, ahi[kt], alo[kt], bp, kt);
    const int q = lane >> 4, mr = lane & 15, c = wave * 16 + mr;
    int r0 = row0 + q * 4;
    int bb = r0 >> 11, n = r0 & 2047;
    int jt = n >> 5, q2 = (n >> 3) & 3, jj = n & 7;
    int h = c >> 4, dd = c & 15;
    size_t off = (((size_t)(bb * 8 + h) * 64 + jt) * 4 + q2) * 128
               + (dd << 3) + jj;
    uint2 st = make_uint2(pk_bf16(acc[0], acc[1]), pk_bf16(acc[2], acc[3]));
    *(uint2*)(vout + off) = st;
}

// ---------------------------------------------------------------------------
// Weight prep + per-row 5th-percentile ranks, fused into one launch.
// ---------------------------------------------------------------------------
struct PrepArgs { const float* src[25]; unsigned vwmask; };

__global__ __launch_bounds__(256) void prep_percentile_kernel(
    PrepArgs a, unsigned short* __restrict__ dst,
    const float* __restrict__ m, float* __restrict__ m102, float* __restrict__ m103)
{
    if (blockIdx.x < 100) {
        const int mat = blockIdx.x >> 2, chunk = blockIdx.x & 3;
        const float* __restrict__ W = a.src[mat];
        const int vw = (a.vwmask >> mat) & 1;
        unsigned short* __restrict__ base = dst + (size_t)mat * 32768;
        for (int o = chunk * 4096 + threadIdx.x; o < chunk * 4096 + 4096; o += 256) {
            int nt = o >> 11, kt = (o >> 9) & 3, q = (o >> 7) & 3;
            int n16 = (o >> 3) & 15, jj = o & 7;
            int k = kt * 32 + q * 8 + jj;
            float w = vw ? W[nt * 2048 + k * 16 + n16]
                         : W[k * 128 + nt * 16 + n16];
            unsigned short h = bf16_rne(w);
            unsigned short l = bf16_rne(w - bf16_to_f(h));
            base[o] = h;
            base[16384 + o] = l;
        }
        return;
    }

    __shared__ int   cnt[256];
    __shared__ int   cum[256];
    __shared__ float buf[192];
    __shared__ int   nc;
    __shared__ int   sb0, sb1, sbase;

    const int row = blockIdx.x - 100;         // 0..4095
    const int t   = threadIdx.x;
    const float* mr = m + (size_t)row * 2048;

    float4 aa = *(const float4*)(mr + t * 8);
    float4 cc = *(const float4*)(mr + t * 8 + 4);
    float v[8] = {aa.x, aa.y, aa.z, aa.w, cc.x, cc.y, cc.z, cc.w};

    cnt[t] = 0;
    if (t == 0) nc = 0;
    __syncthreads();

    int bidx[8];
    #pragma unroll
    for (int i = 0; i < 8; ++i) {
        int bi = (int)(v[i] * 256.0f);
        bi = bi < 0 ? 0 : (bi > 255 ? 255 : bi);
        bidx[i] = bi;
        atomicAdd(&cnt[bi], 1);
    }
    __syncthreads();

    if (t < 64) {
        int c0 = cnt[t * 4], c1 = cnt[t * 4 + 1], c2 = cnt[t * 4 + 2], c3 = cnt[t * 4 + 3];
        int s1 = c0 + c1, s2 = s1 + c2, s3 = s2 + c3;
        int sc = s3;
        #pragma unroll
        for (int off = 1; off < 64; off <<= 1) {
            int o = __shfl_up(sc, off);
            if (t >= off) sc += o;
        }
        int base = sc - s3;
        cum[t * 4]     = base + c0;
        cum[t * 4 + 1] = base + s1;
        cum[t * 4 + 2] = base + s2;
        cum[t * 4 + 3] = base + s3;
    }
    __syncthreads();

    {
        int cprev = (t == 0) ? 0 : cum[t - 1];
        int cthis = cum[t];
        if (cprev < 103 && 103 <= cthis) { sb0 = t; sbase = cprev; }
        if (cprev < 104 && 104 <= cthis) { sb1 = t; }
    }
    __syncthreads();

    const int b0 = sb0, b1 = sb1, base = sbase;
    #pragma unroll
    for (int i = 0; i < 8; ++i) {
        if (bidx[i] >= b0 && bidx[i] <= b1) {
            int p = atomicAdd(&nc, 1);
            if (p < 192) buf[p] = v[i];
        }
    }
    __syncthreads();

    int n = nc; if (n > 192) n = 192;
    if (t < n) {
        float x = buf[t];
        int rk = base;
        for (int j = 0; j < n; ++j) {
            float y = buf[j];
            rk += (y < x || (y == x && j < t)) ? 1 : 0;
        }
        if (rk == 102) m102[row] = x;
        if (rk == 103) m103[row] = x;
    }
}

// ---------------------------------------------------------------------------
// Encoder fused with the first V-projection (256 thr, 4-wave vproj).
// ---------------------------------------------------------------------------
__global__ __launch_bounds__(256) void encoder_vproj_kernel(
    const float* __restrict__ inp, const float* __restrict__ W,
    const float* __restrict__ b, float* __restrict__ ben,
    const unsigned short* __restrict__ Vw, unsigned short* __restrict__ vblk)
{
    __shared__ float xT[16][132];
    const int tid = threadIdx.x;
    const int row0 = blockIdx.x * 16;
    const int ri = tid >> 4, c0 = (tid & 15) * 8;
    const int row = row0 + ri;
    float x0 = inp[row * 3], x1 = inp[row * 3 + 1], x2 = inp[row * 3 + 2];
    float o[8];
    #pragma unroll
    for (int j = 0; j < 8; ++j) {
        int c = c0 + j;
        o[j] = gelu_f(x0 * W[c] + x1 * W[128 + c] + x2 * W[256 + c] + b[c]);
        xT[ri][c0 + j] = o[j];
    }
    *(float4*)(ben + (size_t)row * 128 + c0)     = *(float4*)(o);
    *(float4*)(ben + (size_t)row * 128 + c0 + 4) = *(float4*)(o + 4);
    __syncthreads();
    vproj_lds(xT, row0, Vw, vblk);
}

// ---------------------------------------------------------------------------
// Shared attention stage (stage A): mhpa over 16 rows -> bhT tile in LDS.
// R10-validated: 8 waves (jq x hg), jt loop unrolled x2 with register
// ping-pong, MFMA row-sums vs all-ones B.
// ---------------------------------------------------------------------------
__device__ __forceinline__ void attn_stage(
    const float* __restrict__ m_dist, const unsigned short* __restrict__ vblk,
    const float* __restrict__ rvec,
    const float* __restrict__ m102, const float* __restrict__ m103,
    int masked, int row0,
    float (*partLDS)[16][128], float (*sumLDS)[8][16], float (*bhT)[132])
{
    const int tid  = threadIdx.x;
    const int wave = tid >> 6, lane = tid & 63;
    const int hg = wave & 1, jq = wave >> 1;
    const int q = lane >> 4, rn = lane & 15;
    const int row  = row0 + rn;
    const int b    = row0 >> 11;
    const int n    = row & 2047;

    float r2[4], c2[4], thr[4];
    {
        const double pos = 5.0 / 100.0 * 2047.0;   // tfp percentile position
        const float FRAC = (float)(pos - 102.0);
        const float OM   = 1.0f - FRAC;
        float t102 = m102[row], t103 = m103[row];
        #pragma unroll
        for (int hh = 0; hh < 4; ++hh) {
            float r = rvec[hg * 4 + hh];
            r2[hh] = r * r;
            c2[hh] = -r2[hh] * 1.44269504088896340736f;  // -r^2*log2(e)
            thr[hh] = masked ? ((t102 * r2[hh]) * OM + (t103 * r2[hh]) * FRAC)
                             : 3.4028235e38f;
        }
    }

    const float* mrow = m_dist + ((size_t)b << 22) + ((size_t)n << 11);
    const unsigned short* vbase = vblk + (((size_t)(b * 8 + hg * 4)) << 15);

    f32x4 acc[4], accs[4];
    #pragma unroll
    for (int hh = 0; hh < 4; ++hh) {
        acc[hh]  = (f32x4){0.f, 0.f, 0.f, 0.f};
        accs[hh] = (f32x4){0.f, 0.f, 0.f, 0.f};
    }
    bf16x8 vones;
    #pragma unroll
    for (int j = 0; j < 8; ++j) vones[j] = (short)0x3F80;   // bf16 1.0

    const int jbeg = jq * 16, jend = jbeg + 16;

    float mvA[8], mvB[8]; bf16x8 bfA[4], bfB[4];

    auto loadjt = [&](int jt, float* mv, bf16x8* bf) {
        const int jb = (jt << 5) + (q << 3);
        *(float4*)(mv)     = *(const float4*)(mrow + jb);
        *(float4*)(mv + 4) = *(const float4*)(mrow + jb + 4);
        #pragma unroll
        for (int hh = 0; hh < 4; ++hh)
            bf[hh] = *(const bf16x8*)(vbase + ((size_t)hh << 15)
                                       + ((size_t)jt << 9) + (lane << 3));
    };
    auto compute = [&](const float* mv, const bf16x8* bf) {
        #pragma unroll
        for (int hh = 0; hh < 4; ++hh) {
            float p[8];
            if (masked) {
                #pragma unroll
                for (int jj = 0; jj < 8; ++jj) {
                    float sd = mv[jj] * r2[hh];
                    float e  = __builtin_amdgcn_exp2f(mv[jj] * c2[hh]);
                    p[jj] = (sd <= thr[hh]) ? e : 0.f;
                }
            } else {
                #pragma unroll
                for (int jj = 0; jj < 8; ++jj)
                    p[jj] = __builtin_amdgcn_exp2f(mv[jj] * c2[hh]);
            }
            u32x4 af;
            af[0] = pk_bf16(p[0], p[1]); af[1] = pk_bf16(p[2], p[3]);
            af[2] = pk_bf16(p[4], p[5]); af[3] = pk_bf16(p[6], p[7]);
            bf16x8 afrag = __builtin_bit_cast(bf16x8, af);
            acc[hh]  = __builtin_amdgcn_mfma_f32_16x16x32_bf16(afrag, bf[hh], acc[hh], 0, 0, 0);
            accs[hh] = __builtin_amdgcn_mfma_f32_16x16x32_bf16(afrag, vones,  accs[hh], 0, 0, 0);
        }
    };

    loadjt(jbeg, mvA, bfA);
    for (int jt = jbeg; jt < jend; jt += 2) {
        loadjt(jt + 1, mvB, bfB);
        compute(mvA, bfA);
        int j2 = (jt + 2 < jend) ? jt + 2 : jend - 1;
        loadjt(j2, mvA, bfA);
        compute(mvB, bfB);
    }

    if (rn == 0) {
        #pragma unroll
        for (int hh = 0; hh < 4; ++hh)
            #pragma unroll
            for (int reg = 0; reg < 4; ++reg)
                sumLDS[jq][hg * 4 + hh][q * 4 + reg] = accs[hh][reg];
    }
    #pragma unroll
    for (int hh = 0; hh < 4; ++hh) {
        #pragma unroll
        for (int reg = 0; reg < 4; ++reg)
            partLDS[jq][q * 4 + reg][(hg * 4 + hh) * 16 + rn] = acc[hh][reg];
    }
    __syncthreads();

    // epilogue -> bh tile in LDS
    {
        int e0 = tid << 2;
        int ri = e0 >> 7, c0e = e0 & 127, h = c0e >> 4;
        float4 s = *(const float4*)&partLDS[0][ri][c0e];
        #pragma unroll
        for (int k = 1; k < 4; ++k) {
            float4 pz = *(const float4*)&partLDS[k][ri][c0e];
            s.x += pz.x; s.y += pz.y; s.z += pz.z; s.w += pz.w;
        }
        float l = sumLDS[0][h][ri] + sumLDS[1][h][ri]
                + sumLDS[2][h][ri] + sumLDS[3][h][ri];
        float inv = 1.0f / l;
        float4 o;
        o.x = gelu_f(s.x * inv); o.y = gelu_f(s.y * inv);
        o.z = gelu_f(s.z * inv); o.w = gelu_f(s.w * inv);
        *(float4*)&bhT[ri][c0e] = o;
    }
    __syncthreads();
}

// ---------------------------------------------------------------------------
// Fused processor stage (R11): one kernel per mhpa block.
//   A: attn -> bhT (LDS)
//   B: btT = gelu(bhT @ W1 + b1)                (LDS)
//   C: x'  = gelu(btT @ W2 + xin @ Wi + b2+bi)  -> xout global + xT LDS
//   D: vproj xT through Vw into vout (next stage's V; ping-pong buffer —
//      blocks race across stages otherwise, G16).
// Replaces the former K1+K2 pair: kills 6 dispatch gaps + the bt round-trip.
// ---------------------------------------------------------------------------
__global__ __launch_bounds__(512) void stage_kernel(
    const float* __restrict__ m_dist, const unsigned short* __restrict__ vin,
    const float* __restrict__ rvec,
    const float* __restrict__ m102, const float* __restrict__ m103,
    const unsigned short* __restrict__ W1b, const float* __restrict__ b1,
    const unsigned short* __restrict__ W2b, const float* __restrict__ b2,
    const float* __restrict__ xin, const unsigned short* __restrict__ Wib,
    const float* __restrict__ bi,
    float* __restrict__ xout,
    const unsigned short* __restrict__ Vw, unsigned short* __restrict__ vout,
    int masked)
{
    __shared__ float partLDS[4][16][128];    // 32 KB
    __shared__ float sumLDS[4][8][16];       // 2 KB
    __shared__ float bhT[16][132];
    __shared__ float btT[16][132];
    __shared__ float xT[16][132];

    const int tid = threadIdx.x, wave = tid >> 6, lane = tid & 63;
    const int row0 = blockIdx.x * 16;

    attn_stage(m_dist, vin, rvec, m102, m103, masked, row0,
               partLDS, sumLDS, bhT);

    mm_lds_tile(bhT, btT, W1b, b1, wave, lane);
    __syncthreads();

    mm2_tile(btT, xin, row0, W2b, b2, Wib, bi, xout, xT, wave, lane);
    __syncthreads();

    vproj8(xT, row0, Vw, vout, wave, lane);
}

// ---------------------------------------------------------------------------
// Fused terminal stage: up-mhpa + mlp2 + residual + decoder MLP + final dot.
// ---------------------------------------------------------------------------
__global__ __launch_bounds__(512) void decoder_stage_kernel(
    const float* __restrict__ m_dist, const unsigned short* __restrict__ vin,
    const float* __restrict__ rvec,
    const float* __restrict__ m102, const float* __restrict__ m103,
    const unsigned short* __restrict__ W1b, const float* __restrict__ b1,
    const unsigned short* __restrict__ W2b, const float* __restrict__ b2,
    const float* __restrict__ xin, const unsigned short* __restrict__ Wib,
    const float* __restrict__ bi,
    const unsigned short* __restrict__ DW1, const float* __restrict__ db1,
    const float* __restrict__ de_W2, const float* __restrict__ de_b2,
    float* __restrict__ out)
{
    __shared__ float partLDS[4][16][128];
    __shared__ float sumLDS[4][8][16];
    __shared__ float bhT[16][132];
    __shared__ float btT[16][132];
    __shared__ float xT[16][132];
    __shared__ float tT[16][132];

    const int tid = threadIdx.x, wave = tid >> 6, lane = tid & 63;
    const int row0 = blockIdx.x * 16;

    attn_stage(m_dist, vin, rvec, m102, m103, 1, row0,
               partLDS, sumLDS, bhT);

    mm_lds_tile(bhT, btT, W1b, b1, wave, lane);       // t = gelu(bh@mlp2_W1+b1)
    __syncthreads();

    mm2_tile(btT, xin, row0, W2b, b2, Wib, bi, nullptr, xT, wave, lane);  // de
    __syncthreads();

    mm_lds_tile(xT, tT, DW1, db1, wave, lane);        // t2 = gelu(de@de_W1+b)
    __syncthreads();

    // out = t2 @ de_W2 + de_b2 (16-lane groups reduce one row each)
    if (tid < 256) {
        int r = tid >> 4, ch = tid & 15;
        const float* tp = &tT[r][ch * 8];
        const float* wp = de_W2 + ch * 8;
        float p = 0.f;
        #pragma unroll
        for (int j = 0; j < 8; ++j) p += tp[j] * wp[j];
        p += __shfl_xor(p, 1); p += __shfl_xor(p, 2);
        p += __shfl_xor(p, 4); p += __shfl_xor(p, 8);
        if (ch == 0) out[row0 + r] = p + de_b2[0];
    }
}

// ---------------------------------------------------------------------------
extern "C" void kernel_launch(void* const* d_in, const int* in_sizes, int n_in,
                              void* d_out, int out_size, void* d_ws, size_t ws_size,
                              hipStream_t stream)
{
    (void)in_sizes; (void)n_in; (void)out_size; (void)ws_size;
    const float* m_dist  = (const float*)d_in[0];
    const float* inputs  = (const float*)d_in[1];
    const float* en_W    = (const float*)d_in[2];
    const float* en_b    = (const float*)d_in[3];
    const float* down_r  = (const float*)d_in[4];
    const float* down_w  = (const float*)d_in[5];
    const float* mlp1_W1 = (const float*)d_in[6];
    const float* mlp1_b1 = (const float*)d_in[7];
    const float* mlp1_W2 = (const float*)d_in[8];
    const float* mlp1_b2 = (const float*)d_in[9];
    const float* w1_W    = (const float*)d_in[10];
    const float* w1_b    = (const float*)d_in[11];
    const float* pa_r    = (const float*)d_in[12];
    const float* pa_w    = (const float*)d_in[13];
    const float* blk_W1  = (const float*)d_in[14];
    const float* blk_b1  = (const float*)d_in[15];
    const float* blk_W2  = (const float*)d_in[16];
    const float* blk_b2  = (const float*)d_in[17];
    const float* wi_W    = (const float*)d_in[18];
    const float* wi_b    = (const float*)d_in[19];
    const float* up_r    = (const float*)d_in[20];
    const float* up_w    = (const float*)d_in[21];
    const float* mlp2_W1 = (const float*)d_in[22];
    const float* mlp2_b1 = (const float*)d_in[23];
    const float* mlp2_W2 = (const float*)d_in[24];
    const float* mlp2_b2 = (const float*)d_in[25];
    const float* w2_W    = (const float*)d_in[26];
    const float* w2_b    = (const float*)d_in[27];
    const float* de_W1   = (const float*)d_in[28];
    const float* de_b1   = (const float*)d_in[29];
    const float* de_W2   = (const float*)d_in[30];
    const float* de_b2   = (const float*)d_in[31];
    float* out = (float*)d_out;

    // workspace layout (floats)
    const size_t BUF = (size_t)NROWS * HIDD;   // 524288
    float* w     = (float*)d_ws;
    float* ben   = w;
    float* bx0   = w + 1 * BUF;
    float* bx1   = w + 2 * BUF;
    unsigned short* vblkA = (unsigned short*)(w + 3 * BUF);           // 1 MB
    unsigned short* vblkB = (unsigned short*)(w + 3 * BUF + BUF / 2); // 1 MB
    float* m102  = w + 4 * BUF;
    float* m103  = m102 + NROWS;
    unsigned short* wcvt = (unsigned short*)(m103 + NROWS); // 25 x 64 KB

    enum { CW_DOWN = 0, CW_MLP1W1 = 1, CW_MLP1W2 = 2, CW_W1 = 3,
           CW_PA = 4 /*4..7*/, CW_BLKW1 = 8, CW_BLKW2 = 12, CW_WI = 16,
           CW_UP = 20, CW_MLP2W1 = 21, CW_MLP2W2 = 22, CW_W2 = 23, CW_DE1 = 24 };
    PrepArgs pa;
    pa.src[CW_DOWN]   = down_w;
    pa.src[CW_MLP1W1] = mlp1_W1;
    pa.src[CW_MLP1W2] = mlp1_W2;
    pa.src[CW_W1]     = w1_W;
    for (int i = 0; i < 4; ++i) {
        pa.src[CW_PA + i]    = pa_w   + (size_t)i * NH * HIDD * VD;
        pa.src[CW_BLKW1 + i] = blk_W1 + (size_t)i * HIDD * HIDD;
        pa.src[CW_BLKW2 + i] = blk_W2 + (size_t)i * HIDD * HIDD;
        pa.src[CW_WI + i]    = wi_W   + (size_t)i * HIDD * HIDD;
    }
    pa.src[CW_UP]     = up_w;
    pa.src[CW_MLP2W1] = mlp2_W1;
    pa.src[CW_MLP2W2] = mlp2_W2;
    pa.src[CW_W2]     = w2_W;
    pa.src[CW_DE1]    = de_W1;
    pa.vwmask = (1u << CW_DOWN) | (0xFu << CW_PA) | (1u << CW_UP);

    auto CW = [&](int slot) { return wcvt + (size_t)slot * 32768; };

    dim3 b256(256), b512(512);
    dim3 gT(NROWS / 16);                // 256 tile-blocks

    // weight prep + percentile thresholds (one launch)
    prep_percentile_kernel<<<dim3(100 + NROWS), b256, 0, stream>>>(
        pa, wcvt, m_dist, m102, m103);

    // encoder + V-projection for the down mhpa -> vblkA
    encoder_vproj_kernel<<<gT, b256, 0, stream>>>(inputs, en_W, en_b, ben,
                                                  CW(CW_DOWN), vblkA);

    // down block (fused): reads vblkA, writes bx0 + vblkB (for pa block 0)
    stage_kernel<<<gT, b512, 0, stream>>>(
        m_dist, vblkA, down_r, m102, m103,
        CW(CW_MLP1W1), mlp1_b1, CW(CW_MLP1W2), mlp1_b2,
        ben, CW(CW_W1), w1_b, bx0, CW(CW_PA + 0), vblkB, 1);

    // 4 processor blocks (ping-pong bx0/bx1 and vblkA/vblkB)
    float* xin = bx0;
    float* xout = bx1;
    unsigned short* vin = vblkB;
    unsigned short* vou = vblkA;
    for (int i = 0; i < 4; ++i) {
        stage_kernel<<<gT, b512, 0, stream>>>(
            m_dist, vin, pa_r + (size_t)i * NH, m102, m103,
            CW(CW_BLKW1 + i), blk_b1 + (size_t)i * HIDD,
            CW(CW_BLKW2 + i), blk_b2 + (size_t)i * HIDD,
            xin, CW(CW_WI + i), wi_b + (size_t)i * HIDD,
            xout, (i < 3) ? CW(CW_PA + i + 1) : CW(CW_UP), vou, 0);
        float* t = xin; xin = xout; xout = t;
        unsigned short* tv = vin; vin = vou; vou = tv;
    }
    // xin now holds x; vin holds the up-mhpa V

    // up block + mlp2 + residual + decoder + final (fused terminal kernel)
    decoder_stage_kernel<<<gT, b512, 0, stream>>>(
        m_dist, vin, up_r, m102, m103,
        CW(CW_MLP2W1), mlp2_b1, CW(CW_MLP2W2), mlp2_b2,
        xin, CW(CW_W2), w2_b,
        CW(CW_DE1), de_b1, de_W2, de_b2, out);
}